// Round 14
// baseline (498.739 us; speedup 1.0000x reference)
//
#include <hip/hip_runtime.h>
#include <cstdint>

// SpikingCNN: B=8192, D=784, H=128, O=10, T=20, beta=0.9, thr=1.0
// R14 = R13 with spikegen de-spilled:
//  - thread per (t,b,byte-of-8-d): 16.38M threads; live set ~30 VGPR (r13's
//    T[32] spilled at VGPR_Count=24 -> 155 ops/elem effective).
//  - rotates forced to v_alignbit_b32 (rotl d == alignbit(v,v,32-d)).
//  - 4-lane shfl-OR combine into the same m32 word layout (gemm unchanged);
//    groups aligned since 100 % 4 == 0. Pad d>=784 stores 0 bits (hit only
//    zero weights).
//  Everything else identical to r13 (pass, absmax 0.0).
//  RNG (r9-verified): (x0,x1)=threefry2x32((0,42),(0,n)), n=t*6422528+b*784+d,
//  bits=x0^x1; integer bernoulli (r13-verified): (bits>>9) < ceil(p*2^23).

#define T_STEPS 20
#define B_SZ   8192
#define D_SZ   784
#define H_SZ   128
#define O_SZ   10
#define CUR1_BYTES  83886080u                 // 20*8192*128*4
#define MASKS_OFF   83886080u                 // B1 masks: 20*8192*4*4 = 655360
#define WP_OFF      84541440u                 // weight planes: 3*128*800*2 = 614400
#define M32_OFF     85155840u                 // = WP_OFF + 614400 ; m32: 16384000 B

typedef __attribute__((ext_vector_type(8))) short short8;
typedef __attribute__((ext_vector_type(4))) float f32x4;
typedef unsigned short ushort_t;

__device__ __forceinline__ uint32_t rotl32(uint32_t v, int sh) {
#if __has_builtin(__builtin_amdgcn_alignbit)
  return __builtin_amdgcn_alignbit(v, v, 32 - sh);   // rotr(32-sh) == rotl(sh)
#else
  return (v << sh) | (v >> (32 - sh));
#endif
}

// JAX threefry2x32, key = (0, 42) from jax.random.key(42).
__device__ __forceinline__ void threefry_0_42(uint32_t c0, uint32_t c1,
                                              uint32_t& o0, uint32_t& o1) {
  const uint32_t ks0 = 0u;
  const uint32_t ks1 = 42u;
  const uint32_t ks2 = 0u ^ 42u ^ 0x1BD11BDAu;
  uint32_t x0 = c0 + ks0;
  uint32_t x1 = c1 + ks1;
#define TF_R(rot) { x0 += x1; x1 = rotl32(x1, rot); x1 ^= x0; }
  TF_R(13) TF_R(15) TF_R(26) TF_R(6)
  x0 += ks1; x1 += ks2 + 1u;
  TF_R(17) TF_R(29) TF_R(16) TF_R(24)
  x0 += ks2; x1 += ks0 + 2u;
  TF_R(13) TF_R(15) TF_R(26) TF_R(6)
  x0 += ks0; x1 += ks1 + 3u;
  TF_R(17) TF_R(29) TF_R(16) TF_R(24)
  x0 += ks1; x1 += ks2 + 4u;
  TF_R(13) TF_R(15) TF_R(26) TF_R(6)
  x0 += ks2; x1 += ks0 + 5u;
#undef TF_R
  o0 = x0; o1 = x1;
}

__device__ __forceinline__ uint32_t rne_bf16_bits(float f) {
  uint32_t u = __float_as_uint(f);
  return (u + 0x7fffu + ((u >> 16) & 1u)) & 0xffff0000u;
}

// ---------------------------------------------------------------------------
// P: split w1 f32 [128][784] into 3 exact bf16 planes [128][800] (k-padded 0).
// ---------------------------------------------------------------------------
__global__ __launch_bounds__(256) void split_w1(
    const float* __restrict__ w1, ushort_t* __restrict__ wp) {
  const int h = blockIdx.x;
  for (int k = threadIdx.x; k < 800; k += 256) {
    float w = (k < D_SZ) ? w1[h * D_SZ + k] : 0.0f;
    uint32_t hb = rne_bf16_bits(w);
    float hi = __uint_as_float(hb);
    float r1 = w - hi;                      // exact
    uint32_t mb = rne_bf16_bits(r1);
    float mid = __uint_as_float(mb);
    float lo = r1 - mid;                    // exact, <=8 significant bits
    uint32_t lb = __float_as_uint(lo);
    wp[0 * 102400 + h * 800 + k] = (ushort_t)(hb >> 16);
    wp[1 * 102400 + h * 800 + k] = (ushort_t)(mb >> 16);
    wp[2 * 102400 + h * 800 + k] = (ushort_t)(lb >> 16);
  }
}

// ---------------------------------------------------------------------------
// S: spikegen -> bitmasks. Thread g -> (tb = g/100, byte y = g%100),
// tb = t*8192 + b; d = y*8 + j. Builds one 8-bit group; 4-lane shfl-OR
// assembles the r13 m32 word layout: m32[tb*25 + (y>>2)].
// ---------------------------------------------------------------------------
__global__ __launch_bounds__(256) void spikegen_bits(
    const float* __restrict__ x, uint32_t* __restrict__ m32) {
  const int g  = blockIdx.x * 256 + threadIdx.x;  // 0..16,383,999
  const int tb = g / 100;
  const int y  = g - tb * 100;
  const int b  = tb & 8191;
  const int t  = tb >> 13;
  const int d0 = y << 3;

  uint32_t mybyte = 0u;
  if (d0 < D_SZ) {                                // y <= 97
    const float* xr = x + (size_t)b * D_SZ + d0;
    float4 v0 = *(const float4*)xr;
    float4 v1 = *(const float4*)(xr + 4);
    uint32_t T[8];
    T[0] = (uint32_t)__builtin_ceilf(v0.x * 8388608.0f);
    T[1] = (uint32_t)__builtin_ceilf(v0.y * 8388608.0f);
    T[2] = (uint32_t)__builtin_ceilf(v0.z * 8388608.0f);
    T[3] = (uint32_t)__builtin_ceilf(v0.w * 8388608.0f);
    T[4] = (uint32_t)__builtin_ceilf(v1.x * 8388608.0f);
    T[5] = (uint32_t)__builtin_ceilf(v1.y * 8388608.0f);
    T[6] = (uint32_t)__builtin_ceilf(v1.z * 8388608.0f);
    T[7] = (uint32_t)__builtin_ceilf(v1.w * 8388608.0f);

    const uint32_t nb = (uint32_t)t * 6422528u + (uint32_t)b * 784u +
                        (uint32_t)d0;
#pragma unroll
    for (int j = 0; j < 8; ++j) {
      uint32_t o0, o1;
      threefry_0_42(0u, nb + (uint32_t)j, o0, o1);
      mybyte |= (((o0 ^ o1) >> 9) < T[j]) ? (1u << j) : 0u;
    }
  }

  // combine 4 bytes -> word (groups of 4 lanes aligned: 100 % 4 == 0)
  uint32_t part = mybyte << ((y & 3) * 8);
  part |= __shfl_xor(part, 1);
  part |= __shfl_xor(part, 2);
  if ((y & 3) == 0)
    m32[(size_t)tb * 25 + (y >> 2)] = part;
}

// ---------------------------------------------------------------------------
// G: LDS-free barrier-free MFMA GEMM. grid 1280 x 256 (4 waves = 2x2
// quadrants of a 128x128 C-tile). 25 chunks of k=32; per wave/chunk:
// 4 mask dwords -> in-register A-frag expansion, 12 B-frag dwordx4 loads,
// 48 mfma. Same accumulation order as r10 (absmax 0.0 verified).
// ---------------------------------------------------------------------------
__global__ __launch_bounds__(256) void gemm1_mfma(
    const ushort_t* __restrict__ wp, const uint32_t* __restrict__ m32,
    const float* __restrict__ b1, float* __restrict__ cur1) {
  const int tid  = threadIdx.x;
  const int row0 = blockIdx.x << 7;
  const int wave = tid >> 6, lane = tid & 63;
  const int wr0  = (wave >> 1) << 6;
  const int wc0  = (wave & 1) << 6;
  const int lm   = lane & 15, quad = lane >> 4;
  const int qsh  = quad << 3;          // bit shift AND k-offset (quad*8)

  f32x4 acc[4][4];
#pragma unroll
  for (int m = 0; m < 4; ++m)
#pragma unroll
    for (int nn = 0; nn < 4; ++nn) acc[m][nn] = (f32x4){0.f, 0.f, 0.f, 0.f};

  const uint32_t* mrow = m32 + (size_t)(row0 + wr0 + lm) * 25;
  const ushort_t* wbase = wp + (size_t)(wc0 + lm) * 800 + qsh;

  for (int ko = 0; ko < 25; ++ko) {
    short8 a[4];
#pragma unroll
    for (int m = 0; m < 4; ++m) {
      uint32_t word = mrow[m * 400 + ko];          // row stride 16*25=400
      uint32_t byte = (word >> qsh) & 0xffu;
      short8 av;
#pragma unroll
      for (int j = 0; j < 8; ++j)
        av[j] = (short)(((byte >> j) & 1u) ? 0x3F80 : 0);
      a[m] = av;
    }
    const int kof = ko << 5;
#pragma unroll
    for (int p = 0; p < 3; ++p) {
#pragma unroll
      for (int nn = 0; nn < 4; ++nn) {
        short8 bf = *(const short8*)&wbase[p * 102400 + nn * 16 * 800 + kof];
#pragma unroll
        for (int m = 0; m < 4; ++m)
          acc[m][nn] = __builtin_amdgcn_mfma_f32_16x16x32_bf16(
              a[m], bf, acc[m][nn], 0, 0, 0);
      }
    }
  }

  // epilogue: C/D layout col=lane&15, row=quad*4+reg (r10-verified)
#pragma unroll
  for (int nn = 0; nn < 4; ++nn) {
    int col = wc0 + nn * 16 + lm;
    float bias = b1[col];
#pragma unroll
    for (int m = 0; m < 4; ++m) {
#pragma unroll
      for (int r = 0; r < 4; ++r) {
        int grow = row0 + wr0 + m * 16 + quad * 4 + r;
        cur1[(size_t)grow * H_SZ + col] = acc[m][nn][r] + bias;
      }
    }
  }
}

// ---------------------------------------------------------------------------
// B1: LIF1, 16 lanes/row; lane s owns h = s*8..s*8+7. Identical per-h op
// order to r9/r10. Packs 128-bit mask -> 4 u32 words, coalesced stores.
// ---------------------------------------------------------------------------
__global__ __launch_bounds__(256) void lif1_spikes(
    const float* __restrict__ cur1, uint32_t* __restrict__ masks) {
#pragma clang fp contract(off)
  const int g    = blockIdx.x * 256 + threadIdx.x;  // 0..131071
  const int row  = g >> 4;
  const int s    = g & 15;
  const int lane = threadIdx.x & 63;

  float mem[8];
#pragma unroll
  for (int i = 0; i < 8; ++i) mem[i] = 0.0f;

  for (int t = 0; t < T_STEPS; ++t) {
    const float* base = cur1 + ((size_t)t * B_SZ + row) * H_SZ + s * 8;
    float4 c0 = *(const float4*)base;
    float4 c1 = *(const float4*)(base + 4);
    float cv[8] = {c0.x, c0.y, c0.z, c0.w, c1.x, c1.y, c1.z, c1.w};

    uint32_t bits8 = 0u;
#pragma unroll
    for (int q = 0; q < 8; ++q) {
      float m = mem[q];
      float reset = (m > 1.0f) ? 1.0f : 0.0f;
      m = 0.9f * m;
      m = m + cv[q];
      m = m - reset;
      mem[q] = m;
      bits8 |= (m > 1.0f) ? (1u << q) : 0u;
    }
    uint32_t part = bits8 << ((s & 3) * 8);
    part |= __shfl_xor(part, 1);
    part |= __shfl_xor(part, 2);
    uint32_t myw = __shfl(part, (lane & ~15) + 4 * (s & 3));
    if (s < 4)
      masks[((size_t)t * B_SZ + row) * 4 + s] = myw;
  }
}

// ---------------------------------------------------------------------------
// B2: layer-2 ascending-h add chain + LIF2 (unchanged from r9/r10).
// ---------------------------------------------------------------------------
__global__ __launch_bounds__(320) void lif2_seq(
    const float* __restrict__ w2, const float* __restrict__ b2,
    const uint32_t* __restrict__ masks, float* __restrict__ out) {
#pragma clang fp contract(off)
  __shared__ __align__(16) float sW2[O_SZ][H_SZ];
  const int tid = threadIdx.x;
  for (int i = tid; i < O_SZ * H_SZ; i += 320)
    sW2[i >> 7][i & 127] = w2[i];
  __syncthreads();

  const int wave = tid >> 6;
  const int lane = tid & 63;
  const int row  = ((blockIdx.x >> 1) << 6) + lane;
  const int o    = (blockIdx.x & 1) * 5 + wave;
  const float bias = b2[o];

  float mem2 = 0.0f;
  int cnt = 0;
  const uint4* mbase = (const uint4*)masks;

  for (int t = 0; t < T_STEPS; ++t) {
    uint4 m = mbase[(size_t)t * B_SZ + row];
    uint32_t mw[4] = {m.x, m.y, m.z, m.w};
    float acc = 0.0f;
#pragma unroll
    for (int w = 0; w < 4; ++w) {
#pragma unroll
      for (int hc = 0; hc < 8; ++hc) {
        float4 wv = *(const float4*)&sW2[o][w * 32 + hc * 4];
        float vv[4] = {wv.x, wv.y, wv.z, wv.w};
#pragma unroll
        for (int bb = 0; bb < 4; ++bb) {
          float val = ((mw[w] >> (hc * 4 + bb)) & 1u) ? vv[bb] : 0.0f;
          acc = acc + val;
        }
      }
    }
    float c2 = acc + bias;
    float reset = (mem2 > 1.0f) ? 1.0f : 0.0f;
    mem2 = 0.9f * mem2;
    mem2 = mem2 + c2;
    mem2 = mem2 - reset;
    cnt += (mem2 > 1.0f) ? 1 : 0;
  }
  out[row * O_SZ + o] = (float)cnt / 20.0f;
}

extern "C" void kernel_launch(void* const* d_in, const int* in_sizes, int n_in,
                              void* d_out, int out_size, void* d_ws, size_t ws_size,
                              hipStream_t stream) {
  const float* x   = (const float*)d_in[0];  // [8192,784]
  const float* w1  = (const float*)d_in[1];  // [128,784]
  const float* b1  = (const float*)d_in[2];  // [128]
  const float* w2  = (const float*)d_in[3];  // [10,128]
  const float* b2  = (const float*)d_in[4];  // [10]
  float* out  = (float*)d_out;               // [8192,10]
  float*    cur1  = (float*)d_ws;
  uint32_t* masks = (uint32_t*)((char*)d_ws + MASKS_OFF);
  ushort_t* wp    = (ushort_t*)((char*)d_ws + WP_OFF);
  uint32_t* m32   = (uint32_t*)((char*)d_ws + M32_OFF);

  split_w1     <<<dim3(128),   dim3(256), 0, stream>>>(w1, wp);
  spikegen_bits<<<dim3(64000), dim3(256), 0, stream>>>(x, m32);
  gemm1_mfma   <<<dim3(1280),  dim3(256), 0, stream>>>(wp, m32, b1, cur1);
  lif1_spikes  <<<dim3(512),   dim3(256), 0, stream>>>(cur1, masks);
  lif2_seq     <<<dim3(256),   dim3(320), 0, stream>>>(w2, b2, masks, out);
}

// Round 15
// 453.120 us; speedup vs baseline: 1.1007x; 1.1007x over previous
//
#include <hip/hip_runtime.h>
#include <cstdint>

// SpikingCNN: B=8192, D=784, H=128, O=10, T=20, beta=0.9, thr=1.0
// R15 = R14 with spikegen instruction-count attack (was 162 VALU/elem vs ~80
// ideal; 56% of total runtime):
//  - rotl via inline-asm v_alignbit_b32 (1 instr/round guaranteed).
//  - integer thresholds T=ceil(p*2^23) precomputed once per (b,d) into ws
//    (26 MB) by the prep kernel (fused with w1 split); spikegen loads them
//    (drops mul+ceil+cvt per element, was recomputed 20x).
//  - byte store m8[g] (little-endian == old m32 word layout; gemm unchanged).
//  - nb = tb*784 + d0 (one mad).
//  RNG (r9-verified): (x0,x1)=threefry2x32((0,42),(0,n)), n=tb*784+d,
//  bits=x0^x1; integer bernoulli (r13-verified): (bits>>9) < ceil(p*2^23).
//  G/B1/B2 byte-identical to r14 (pass, absmax 0.0).

#define T_STEPS 20
#define B_SZ   8192
#define D_SZ   784
#define H_SZ   128
#define O_SZ   10
#define CUR1_BYTES  83886080u                 // 20*8192*128*4
#define MASKS_OFF   83886080u                 // B1 masks: 655360 B
#define WP_OFF      84541440u                 // weight planes: 614400 B
#define M32_OFF     85155840u                 // spike bits: 16384000 B
#define THR_OFF     101539840u                // thresholds: 8192*800*4 = 26214400 B

typedef __attribute__((ext_vector_type(8))) short short8;
typedef __attribute__((ext_vector_type(4))) float f32x4;
typedef unsigned short ushort_t;

// rotl via v_alignbit_b32: rotl(v,s) == rotr(v,32-s) == alignbit(v,v,32-s).
// 32-s in {19,17,6,26,15,3,16,8} are valid VOP3 inline constants.
#define ROTL_ASM(dst, src, sh)                                        \
  asm("v_alignbit_b32 %0, %1, %1, %2" : "=v"(dst) : "v"(src), "n"(32 - (sh)))

// JAX threefry2x32, key = (0, 42) from jax.random.key(42).
__device__ __forceinline__ void threefry_0_42(uint32_t c0, uint32_t c1,
                                              uint32_t& o0, uint32_t& o1) {
  const uint32_t ks0 = 0u;
  const uint32_t ks1 = 42u;
  const uint32_t ks2 = 0u ^ 42u ^ 0x1BD11BDAu;
  uint32_t x0 = c0 + ks0;
  uint32_t x1 = c1 + ks1;
  uint32_t r;
#define TF_R(rot) { x0 += x1; ROTL_ASM(r, x1, rot); x1 = r ^ x0; }
  TF_R(13) TF_R(15) TF_R(26) TF_R(6)
  x0 += ks1; x1 += ks2 + 1u;
  TF_R(17) TF_R(29) TF_R(16) TF_R(24)
  x0 += ks2; x1 += ks0 + 2u;
  TF_R(13) TF_R(15) TF_R(26) TF_R(6)
  x0 += ks0; x1 += ks1 + 3u;
  TF_R(17) TF_R(29) TF_R(16) TF_R(24)
  x0 += ks1; x1 += ks2 + 4u;
  TF_R(13) TF_R(15) TF_R(26) TF_R(6)
  x0 += ks2; x1 += ks0 + 5u;
#undef TF_R
  o0 = x0; o1 = x1;
}

__device__ __forceinline__ uint32_t rne_bf16_bits(float f) {
  uint32_t u = __float_as_uint(f);
  return (u + 0x7fffu + ((u >> 16) & 1u)) & 0xffff0000u;
}

// ---------------------------------------------------------------------------
// P: prep. Blocks 0..127: split w1 into 3 exact bf16 planes [128][800].
// Blocks 128..3327: integer thresholds thresh[b][d8] = ceil(x*2^23),
// d in [0,800) padded with 0 (==never spikes; identical to r13/r14 padding).
// ---------------------------------------------------------------------------
__global__ __launch_bounds__(256) void prep(
    const float* __restrict__ w1, const float* __restrict__ x,
    ushort_t* __restrict__ wp, uint32_t* __restrict__ thresh) {
  if (blockIdx.x < 128) {
    const int h = blockIdx.x;
    for (int k = threadIdx.x; k < 800; k += 256) {
      float w = (k < D_SZ) ? w1[h * D_SZ + k] : 0.0f;
      uint32_t hb = rne_bf16_bits(w);
      float hi = __uint_as_float(hb);
      float r1 = w - hi;                      // exact
      uint32_t mb = rne_bf16_bits(r1);
      float mid = __uint_as_float(mb);
      float lo = r1 - mid;                    // exact
      uint32_t lb = __float_as_uint(lo);
      wp[0 * 102400 + h * 800 + k] = (ushort_t)(hb >> 16);
      wp[1 * 102400 + h * 800 + k] = (ushort_t)(mb >> 16);
      wp[2 * 102400 + h * 800 + k] = (ushort_t)(lb >> 16);
    }
  } else {
    const int gid = (blockIdx.x - 128) * 256 + threadIdx.x;  // 0..819199
    const int b = gid / 100;
    const int y = gid - b * 100;
    const int d0 = y << 3;
    uint4 T0 = {0u, 0u, 0u, 0u}, T1 = {0u, 0u, 0u, 0u};
    if (y < 98) {                                  // d0+7 <= 783
      const float* xr = x + (size_t)b * D_SZ + d0;
      float4 v0 = *(const float4*)xr;
      float4 v1 = *(const float4*)(xr + 4);
      T0.x = (uint32_t)__builtin_ceilf(v0.x * 8388608.0f);
      T0.y = (uint32_t)__builtin_ceilf(v0.y * 8388608.0f);
      T0.z = (uint32_t)__builtin_ceilf(v0.z * 8388608.0f);
      T0.w = (uint32_t)__builtin_ceilf(v0.w * 8388608.0f);
      T1.x = (uint32_t)__builtin_ceilf(v1.x * 8388608.0f);
      T1.y = (uint32_t)__builtin_ceilf(v1.y * 8388608.0f);
      T1.z = (uint32_t)__builtin_ceilf(v1.z * 8388608.0f);
      T1.w = (uint32_t)__builtin_ceilf(v1.w * 8388608.0f);
    }
    uint32_t* tp = thresh + (size_t)b * 800 + d0;
    *(uint4*)tp       = T0;
    *(uint4*)(tp + 4) = T1;
  }
}

// ---------------------------------------------------------------------------
// S: spikegen -> bit bytes. Thread g -> (tb = g/100, y = g%100); d = y*8+j.
// Stores m8[g] (little-endian bytes == r13/r14 m32 word layout).
// ---------------------------------------------------------------------------
__global__ __launch_bounds__(256) void spikegen_bits(
    const uint32_t* __restrict__ thresh, uint8_t* __restrict__ m8) {
  const int g  = blockIdx.x * 256 + threadIdx.x;  // 0..16,383,999
  const int tb = g / 100;
  const int y  = g - tb * 100;
  const int b  = tb & 8191;
  const int d0 = y << 3;

  const uint32_t* tp = thresh + (size_t)b * 800 + d0;
  uint4 T0 = *(const uint4*)tp;
  uint4 T1 = *(const uint4*)(tp + 4);
  uint32_t T[8] = {T0.x, T0.y, T0.z, T0.w, T1.x, T1.y, T1.z, T1.w};

  const uint32_t nb = (uint32_t)tb * 784u + (uint32_t)d0;
  uint32_t mybyte = 0u;
#pragma unroll
  for (int j = 0; j < 8; ++j) {
    uint32_t o0, o1;
    threefry_0_42(0u, nb + (uint32_t)j, o0, o1);
    mybyte |= (((o0 ^ o1) >> 9) < T[j]) ? (1u << j) : 0u;
  }
  m8[g] = (uint8_t)mybyte;
}

// ---------------------------------------------------------------------------
// G: LDS-free barrier-free MFMA GEMM (byte-identical to r12-r14; absmax 0.0).
// ---------------------------------------------------------------------------
__global__ __launch_bounds__(256) void gemm1_mfma(
    const ushort_t* __restrict__ wp, const uint32_t* __restrict__ m32,
    const float* __restrict__ b1, float* __restrict__ cur1) {
  const int tid  = threadIdx.x;
  const int row0 = blockIdx.x << 7;
  const int wave = tid >> 6, lane = tid & 63;
  const int wr0  = (wave >> 1) << 6;
  const int wc0  = (wave & 1) << 6;
  const int lm   = lane & 15, quad = lane >> 4;
  const int qsh  = quad << 3;

  f32x4 acc[4][4];
#pragma unroll
  for (int m = 0; m < 4; ++m)
#pragma unroll
    for (int nn = 0; nn < 4; ++nn) acc[m][nn] = (f32x4){0.f, 0.f, 0.f, 0.f};

  const uint32_t* mrow = m32 + (size_t)(row0 + wr0 + lm) * 25;
  const ushort_t* wbase = wp + (size_t)(wc0 + lm) * 800 + qsh;

  for (int ko = 0; ko < 25; ++ko) {
    short8 a[4];
#pragma unroll
    for (int m = 0; m < 4; ++m) {
      uint32_t word = mrow[m * 400 + ko];
      uint32_t byte = (word >> qsh) & 0xffu;
      short8 av;
#pragma unroll
      for (int j = 0; j < 8; ++j)
        av[j] = (short)(((byte >> j) & 1u) ? 0x3F80 : 0);
      a[m] = av;
    }
    const int kof = ko << 5;
#pragma unroll
    for (int p = 0; p < 3; ++p) {
#pragma unroll
      for (int nn = 0; nn < 4; ++nn) {
        short8 bf = *(const short8*)&wbase[p * 102400 + nn * 16 * 800 + kof];
#pragma unroll
        for (int m = 0; m < 4; ++m)
          acc[m][nn] = __builtin_amdgcn_mfma_f32_16x16x32_bf16(
              a[m], bf, acc[m][nn], 0, 0, 0);
      }
    }
  }

#pragma unroll
  for (int nn = 0; nn < 4; ++nn) {
    int col = wc0 + nn * 16 + lm;
    float bias = b1[col];
#pragma unroll
    for (int m = 0; m < 4; ++m) {
#pragma unroll
      for (int r = 0; r < 4; ++r) {
        int grow = row0 + wr0 + m * 16 + quad * 4 + r;
        cur1[(size_t)grow * H_SZ + col] = acc[m][nn][r] + bias;
      }
    }
  }
}

// ---------------------------------------------------------------------------
// B1: LIF1, 16 lanes/row (byte-identical to r13/r14; absmax 0.0).
// ---------------------------------------------------------------------------
__global__ __launch_bounds__(256) void lif1_spikes(
    const float* __restrict__ cur1, uint32_t* __restrict__ masks) {
#pragma clang fp contract(off)
  const int g    = blockIdx.x * 256 + threadIdx.x;
  const int row  = g >> 4;
  const int s    = g & 15;
  const int lane = threadIdx.x & 63;

  float mem[8];
#pragma unroll
  for (int i = 0; i < 8; ++i) mem[i] = 0.0f;

  for (int t = 0; t < T_STEPS; ++t) {
    const float* base = cur1 + ((size_t)t * B_SZ + row) * H_SZ + s * 8;
    float4 c0 = *(const float4*)base;
    float4 c1 = *(const float4*)(base + 4);
    float cv[8] = {c0.x, c0.y, c0.z, c0.w, c1.x, c1.y, c1.z, c1.w};

    uint32_t bits8 = 0u;
#pragma unroll
    for (int q = 0; q < 8; ++q) {
      float m = mem[q];
      float reset = (m > 1.0f) ? 1.0f : 0.0f;
      m = 0.9f * m;
      m = m + cv[q];
      m = m - reset;
      mem[q] = m;
      bits8 |= (m > 1.0f) ? (1u << q) : 0u;
    }
    uint32_t part = bits8 << ((s & 3) * 8);
    part |= __shfl_xor(part, 1);
    part |= __shfl_xor(part, 2);
    uint32_t myw = __shfl(part, (lane & ~15) + 4 * (s & 3));
    if (s < 4)
      masks[((size_t)t * B_SZ + row) * 4 + s] = myw;
  }
}

// ---------------------------------------------------------------------------
// B2: layer-2 ascending-h add chain + LIF2 (byte-identical to r9-r14).
// ---------------------------------------------------------------------------
__global__ __launch_bounds__(320) void lif2_seq(
    const float* __restrict__ w2, const float* __restrict__ b2,
    const uint32_t* __restrict__ masks, float* __restrict__ out) {
#pragma clang fp contract(off)
  __shared__ __align__(16) float sW2[O_SZ][H_SZ];
  const int tid = threadIdx.x;
  for (int i = tid; i < O_SZ * H_SZ; i += 320)
    sW2[i >> 7][i & 127] = w2[i];
  __syncthreads();

  const int wave = tid >> 6;
  const int lane = tid & 63;
  const int row  = ((blockIdx.x >> 1) << 6) + lane;
  const int o    = (blockIdx.x & 1) * 5 + wave;
  const float bias = b2[o];

  float mem2 = 0.0f;
  int cnt = 0;
  const uint4* mbase = (const uint4*)masks;

  for (int t = 0; t < T_STEPS; ++t) {
    uint4 m = mbase[(size_t)t * B_SZ + row];
    uint32_t mw[4] = {m.x, m.y, m.z, m.w};
    float acc = 0.0f;
#pragma unroll
    for (int w = 0; w < 4; ++w) {
#pragma unroll
      for (int hc = 0; hc < 8; ++hc) {
        float4 wv = *(const float4*)&sW2[o][w * 32 + hc * 4];
        float vv[4] = {wv.x, wv.y, wv.z, wv.w};
#pragma unroll
        for (int bb = 0; bb < 4; ++bb) {
          float val = ((mw[w] >> (hc * 4 + bb)) & 1u) ? vv[bb] : 0.0f;
          acc = acc + val;
        }
      }
    }
    float c2 = acc + bias;
    float reset = (mem2 > 1.0f) ? 1.0f : 0.0f;
    mem2 = 0.9f * mem2;
    mem2 = mem2 + c2;
    mem2 = mem2 - reset;
    cnt += (mem2 > 1.0f) ? 1 : 0;
  }
  out[row * O_SZ + o] = (float)cnt / 20.0f;
}

extern "C" void kernel_launch(void* const* d_in, const int* in_sizes, int n_in,
                              void* d_out, int out_size, void* d_ws, size_t ws_size,
                              hipStream_t stream) {
  const float* x   = (const float*)d_in[0];  // [8192,784]
  const float* w1  = (const float*)d_in[1];  // [128,784]
  const float* b1  = (const float*)d_in[2];  // [128]
  const float* w2  = (const float*)d_in[3];  // [10,128]
  const float* b2  = (const float*)d_in[4];  // [10]
  float* out  = (float*)d_out;               // [8192,10]
  float*    cur1   = (float*)d_ws;
  uint32_t* masks  = (uint32_t*)((char*)d_ws + MASKS_OFF);
  ushort_t* wp     = (ushort_t*)((char*)d_ws + WP_OFF);
  uint32_t* m32    = (uint32_t*)((char*)d_ws + M32_OFF);
  uint8_t*  m8     = (uint8_t*)((char*)d_ws + M32_OFF);
  uint32_t* thresh = (uint32_t*)((char*)d_ws + THR_OFF);

  prep         <<<dim3(3328),  dim3(256), 0, stream>>>(w1, x, wp, thresh);
  spikegen_bits<<<dim3(64000), dim3(256), 0, stream>>>(thresh, m8);
  gemm1_mfma   <<<dim3(1280),  dim3(256), 0, stream>>>(wp, m32, b1, cur1);
  lif1_spikes  <<<dim3(512),   dim3(256), 0, stream>>>(cur1, masks);
  lif2_seq     <<<dim3(256),   dim3(320), 0, stream>>>(w2, b2, masks, out);
}

// Round 16
// 444.385 us; speedup vs baseline: 1.1223x; 1.0197x over previous
//
#include <hip/hip_runtime.h>
#include <cstdint>

// SpikingCNN: B=8192, D=784, H=128, O=10, T=20, beta=0.9, thr=1.0
// R16: fuse spikegen+gemm into ONE kernel to overlap the VALU pipe (threefry,
// ~131us of work) with the MFMA pipe (~49us) across desynced blocks (m114
// co-scheduling). Unlike r10's failed fusion: LDS = 12.8KB of bitmasks (not
// 40KB bf16) and ONE barrier per block (not 2/chunk). Removes the 16MB m32
// round-trip. Micro-opts (both exact):
//  - prep stores pre-shifted Ts = ceil(x*2^23)<<9 ; bits>>9 < T <=> bits < Ts
//    (T <= 2^23-1 since x on the 2^-23 grid -> no overflow).
//  - cmp+addc 2-instr bit accumulate (j descending), asm vcc chain.
//  RNG (r9-verified): (x0,x1)=threefry2x32((0,42),(0,n)), n=tb*784+d,
//  bits=x0^x1. GEMM accumulation order / C-layout: r10/r12-verified.
//  prep(w1-split part) / lif1 / lif2 byte-identical to r15 (absmax 0.0).

#define T_STEPS 20
#define B_SZ   8192
#define D_SZ   784
#define H_SZ   128
#define O_SZ   10
#define CUR1_BYTES  83886080u                 // 20*8192*128*4
#define MASKS_OFF   83886080u                 // B1 masks: 655360 B
#define WP_OFF      84541440u                 // weight planes: 614400 B
#define THR_OFF     101539840u                // thresholds: 8192*800*4 = 26214400 B

typedef __attribute__((ext_vector_type(8))) short short8;
typedef __attribute__((ext_vector_type(4))) float f32x4;
typedef unsigned short ushort_t;

// rotl via v_alignbit_b32 (r15-verified: 1 instr/round).
#define ROTL_ASM(dst, src, sh)                                        \
  asm("v_alignbit_b32 %0, %1, %1, %2" : "=v"(dst) : "v"(src), "n"(32 - (sh)))

// JAX threefry2x32, key = (0, 42) from jax.random.key(42).
__device__ __forceinline__ void threefry_0_42(uint32_t c0, uint32_t c1,
                                              uint32_t& o0, uint32_t& o1) {
  const uint32_t ks0 = 0u;
  const uint32_t ks1 = 42u;
  const uint32_t ks2 = 0u ^ 42u ^ 0x1BD11BDAu;
  uint32_t x0 = c0 + ks0;
  uint32_t x1 = c1 + ks1;
  uint32_t r;
#define TF_R(rot) { x0 += x1; ROTL_ASM(r, x1, rot); x1 = r ^ x0; }
  TF_R(13) TF_R(15) TF_R(26) TF_R(6)
  x0 += ks1; x1 += ks2 + 1u;
  TF_R(17) TF_R(29) TF_R(16) TF_R(24)
  x0 += ks2; x1 += ks0 + 2u;
  TF_R(13) TF_R(15) TF_R(26) TF_R(6)
  x0 += ks0; x1 += ks1 + 3u;
  TF_R(17) TF_R(29) TF_R(16) TF_R(24)
  x0 += ks1; x1 += ks2 + 4u;
  TF_R(13) TF_R(15) TF_R(26) TF_R(6)
  x0 += ks2; x1 += ks0 + 5u;
#undef TF_R
  o0 = x0; o1 = x1;
}

__device__ __forceinline__ uint32_t rne_bf16_bits(float f) {
  uint32_t u = __float_as_uint(f);
  return (u + 0x7fffu + ((u >> 16) & 1u)) & 0xffff0000u;
}

// ---------------------------------------------------------------------------
// P: prep. Blocks 0..127: split w1 into 3 exact bf16 planes [128][800].
// Blocks 128..3327: pre-shifted thresholds thresh[b][d] = ceil(x*2^23)<<9,
// d in [784,800) padded 0 (never spikes; hits only zero weights).
// ---------------------------------------------------------------------------
__global__ __launch_bounds__(256) void prep(
    const float* __restrict__ w1, const float* __restrict__ x,
    ushort_t* __restrict__ wp, uint32_t* __restrict__ thresh) {
  if (blockIdx.x < 128) {
    const int h = blockIdx.x;
    for (int k = threadIdx.x; k < 800; k += 256) {
      float w = (k < D_SZ) ? w1[h * D_SZ + k] : 0.0f;
      uint32_t hb = rne_bf16_bits(w);
      float hi = __uint_as_float(hb);
      float r1 = w - hi;                      // exact
      uint32_t mb = rne_bf16_bits(r1);
      float mid = __uint_as_float(mb);
      float lo = r1 - mid;                    // exact
      uint32_t lb = __float_as_uint(lo);
      wp[0 * 102400 + h * 800 + k] = (ushort_t)(hb >> 16);
      wp[1 * 102400 + h * 800 + k] = (ushort_t)(mb >> 16);
      wp[2 * 102400 + h * 800 + k] = (ushort_t)(lb >> 16);
    }
  } else {
    const int gid = (blockIdx.x - 128) * 256 + threadIdx.x;  // 0..819199
    const int b = gid / 100;
    const int y = gid - b * 100;
    const int d0 = y << 3;
    uint4 T0 = {0u, 0u, 0u, 0u}, T1 = {0u, 0u, 0u, 0u};
    if (y < 98) {                                  // d0+7 <= 783
      const float* xr = x + (size_t)b * D_SZ + d0;
      float4 v0 = *(const float4*)xr;
      float4 v1 = *(const float4*)(xr + 4);
      T0.x = (uint32_t)__builtin_ceilf(v0.x * 8388608.0f) << 9;
      T0.y = (uint32_t)__builtin_ceilf(v0.y * 8388608.0f) << 9;
      T0.z = (uint32_t)__builtin_ceilf(v0.z * 8388608.0f) << 9;
      T0.w = (uint32_t)__builtin_ceilf(v0.w * 8388608.0f) << 9;
      T1.x = (uint32_t)__builtin_ceilf(v1.x * 8388608.0f) << 9;
      T1.y = (uint32_t)__builtin_ceilf(v1.y * 8388608.0f) << 9;
      T1.z = (uint32_t)__builtin_ceilf(v1.z * 8388608.0f) << 9;
      T1.w = (uint32_t)__builtin_ceilf(v1.w * 8388608.0f) << 9;
    }
    uint32_t* tp = thresh + (size_t)b * 800 + d0;
    *(uint4*)tp       = T0;
    *(uint4*)(tp + 4) = T1;
  }
}

// ---------------------------------------------------------------------------
// SG: fused spikegen + MFMA GEMM. grid 1280 x 256. Block bid: t = bid>>6,
// b0 = (bid&63)*128; flat row0 = bid*128 (== t*8192+b0).
// Phase 1: 3200 mask words -> LDS (each thread 12-13 words; 32 threefry/word,
//          cmp+addc accumulate). Phase 2 (after ONE barrier): r12 MFMA loop
//          with mask words read from LDS (stride 25 dwords -> conflict-free).
// ---------------------------------------------------------------------------
__global__ __launch_bounds__(256) void spike_gemm(
    const uint32_t* __restrict__ thresh, const ushort_t* __restrict__ wp,
    const float* __restrict__ b1, float* __restrict__ cur1) {
  __shared__ uint32_t sM[128 * 25];   // 12.8 KB mask words [row][w]

  const int tid  = threadIdx.x;
  const int row0 = blockIdx.x << 7;   // flat row = t*8192 + b
  const int b0   = (blockIdx.x & 63) << 7;

  // ---- phase 1: spikegen into LDS ----
  for (int idx = tid; idx < 3200; idx += 256) {
    int r = idx / 25;                 // 0..127
    int w = idx - r * 25;             // 0..24
    int b = b0 + r;
    const uint32_t* tp = thresh + (size_t)b * 800 + (w << 5);
    uint32_t Ts[32];
#pragma unroll
    for (int q = 0; q < 8; ++q) {
      uint4 v = *(const uint4*)(tp + q * 4);
      Ts[q * 4 + 0] = v.x; Ts[q * 4 + 1] = v.y;
      Ts[q * 4 + 2] = v.z; Ts[q * 4 + 3] = v.w;
    }
    const uint32_t nw = (uint32_t)(row0 + r) * 784u + ((uint32_t)w << 5);
    uint32_t word = 0u;
#pragma unroll
    for (int j = 31; j >= 0; --j) {   // descending: bit for j lands at pos j
      uint32_t o0, o1;
      threefry_0_42(0u, nw + (uint32_t)j, o0, o1);
      uint32_t bits = o0 ^ o1;
      asm("v_cmp_lt_u32 vcc, %1, %2\n\t"
          "v_addc_co_u32 %0, vcc, %0, %0, vcc"
          : "+v"(word) : "v"(bits), "v"(Ts[j]) : "vcc");
    }
    sM[idx] = word;
  }
  __syncthreads();

  // ---- phase 2: MFMA GEMM (r12-verified structure/order) ----
  const int wave = tid >> 6, lane = tid & 63;
  const int wr0  = (wave >> 1) << 6;
  const int wc0  = (wave & 1) << 6;
  const int lm   = lane & 15, quad = lane >> 4;
  const int qsh  = quad << 3;

  f32x4 acc[4][4];
#pragma unroll
  for (int m = 0; m < 4; ++m)
#pragma unroll
    for (int nn = 0; nn < 4; ++nn) acc[m][nn] = (f32x4){0.f, 0.f, 0.f, 0.f};

  const ushort_t* wbase = wp + (size_t)(wc0 + lm) * 800 + qsh;
  const uint32_t* mrow  = &sM[(wr0 + lm) * 25];

  for (int ko = 0; ko < 25; ++ko) {
    short8 a[4];
#pragma unroll
    for (int m = 0; m < 4; ++m) {
      uint32_t word = mrow[m * 400 + ko];          // LDS, stride 16*25 dwords
      uint32_t byte = (word >> qsh) & 0xffu;
      short8 av;
#pragma unroll
      for (int j = 0; j < 8; ++j)
        av[j] = (short)(((byte >> j) & 1u) ? 0x3F80 : 0);
      a[m] = av;
    }
    const int kof = ko << 5;
#pragma unroll
    for (int p = 0; p < 3; ++p) {
#pragma unroll
      for (int nn = 0; nn < 4; ++nn) {
        short8 bf = *(const short8*)&wbase[p * 102400 + nn * 16 * 800 + kof];
#pragma unroll
        for (int m = 0; m < 4; ++m)
          acc[m][nn] = __builtin_amdgcn_mfma_f32_16x16x32_bf16(
              a[m], bf, acc[m][nn], 0, 0, 0);
      }
    }
  }

  // epilogue: C/D layout col=lane&15, row=quad*4+reg (r10-verified)
#pragma unroll
  for (int nn = 0; nn < 4; ++nn) {
    int col = wc0 + nn * 16 + lm;
    float bias = b1[col];
#pragma unroll
    for (int m = 0; m < 4; ++m) {
#pragma unroll
      for (int r = 0; r < 4; ++r) {
        int grow = row0 + wr0 + m * 16 + quad * 4 + r;
        cur1[(size_t)grow * H_SZ + col] = acc[m][nn][r] + bias;
      }
    }
  }
}

// ---------------------------------------------------------------------------
// B1: LIF1, 16 lanes/row (byte-identical to r13-r15; absmax 0.0).
// ---------------------------------------------------------------------------
__global__ __launch_bounds__(256) void lif1_spikes(
    const float* __restrict__ cur1, uint32_t* __restrict__ masks) {
#pragma clang fp contract(off)
  const int g    = blockIdx.x * 256 + threadIdx.x;
  const int row  = g >> 4;
  const int s    = g & 15;
  const int lane = threadIdx.x & 63;

  float mem[8];
#pragma unroll
  for (int i = 0; i < 8; ++i) mem[i] = 0.0f;

  for (int t = 0; t < T_STEPS; ++t) {
    const float* base = cur1 + ((size_t)t * B_SZ + row) * H_SZ + s * 8;
    float4 c0 = *(const float4*)base;
    float4 c1 = *(const float4*)(base + 4);
    float cv[8] = {c0.x, c0.y, c0.z, c0.w, c1.x, c1.y, c1.z, c1.w};

    uint32_t bits8 = 0u;
#pragma unroll
    for (int q = 0; q < 8; ++q) {
      float m = mem[q];
      float reset = (m > 1.0f) ? 1.0f : 0.0f;
      m = 0.9f * m;
      m = m + cv[q];
      m = m - reset;
      mem[q] = m;
      bits8 |= (m > 1.0f) ? (1u << q) : 0u;
    }
    uint32_t part = bits8 << ((s & 3) * 8);
    part |= __shfl_xor(part, 1);
    part |= __shfl_xor(part, 2);
    uint32_t myw = __shfl(part, (lane & ~15) + 4 * (s & 3));
    if (s < 4)
      masks[((size_t)t * B_SZ + row) * 4 + s] = myw;
  }
}

// ---------------------------------------------------------------------------
// B2: layer-2 ascending-h add chain + LIF2 (byte-identical to r9-r15).
// ---------------------------------------------------------------------------
__global__ __launch_bounds__(320) void lif2_seq(
    const float* __restrict__ w2, const float* __restrict__ b2,
    const uint32_t* __restrict__ masks, float* __restrict__ out) {
#pragma clang fp contract(off)
  __shared__ __align__(16) float sW2[O_SZ][H_SZ];
  const int tid = threadIdx.x;
  for (int i = tid; i < O_SZ * H_SZ; i += 320)
    sW2[i >> 7][i & 127] = w2[i];
  __syncthreads();

  const int wave = tid >> 6;
  const int lane = tid & 63;
  const int row  = ((blockIdx.x >> 1) << 6) + lane;
  const int o    = (blockIdx.x & 1) * 5 + wave;
  const float bias = b2[o];

  float mem2 = 0.0f;
  int cnt = 0;
  const uint4* mbase = (const uint4*)masks;

  for (int t = 0; t < T_STEPS; ++t) {
    uint4 m = mbase[(size_t)t * B_SZ + row];
    uint32_t mw[4] = {m.x, m.y, m.z, m.w};
    float acc = 0.0f;
#pragma unroll
    for (int w = 0; w < 4; ++w) {
#pragma unroll
      for (int hc = 0; hc < 8; ++hc) {
        float4 wv = *(const float4*)&sW2[o][w * 32 + hc * 4];
        float vv[4] = {wv.x, wv.y, wv.z, wv.w};
#pragma unroll
        for (int bb = 0; bb < 4; ++bb) {
          float val = ((mw[w] >> (hc * 4 + bb)) & 1u) ? vv[bb] : 0.0f;
          acc = acc + val;
        }
      }
    }
    float c2 = acc + bias;
    float reset = (mem2 > 1.0f) ? 1.0f : 0.0f;
    mem2 = 0.9f * mem2;
    mem2 = mem2 + c2;
    mem2 = mem2 - reset;
    cnt += (mem2 > 1.0f) ? 1 : 0;
  }
  out[row * O_SZ + o] = (float)cnt / 20.0f;
}

extern "C" void kernel_launch(void* const* d_in, const int* in_sizes, int n_in,
                              void* d_out, int out_size, void* d_ws, size_t ws_size,
                              hipStream_t stream) {
  const float* x   = (const float*)d_in[0];  // [8192,784]
  const float* w1  = (const float*)d_in[1];  // [128,784]
  const float* b1  = (const float*)d_in[2];  // [128]
  const float* w2  = (const float*)d_in[3];  // [10,128]
  const float* b2  = (const float*)d_in[4];  // [10]
  float* out  = (float*)d_out;               // [8192,10]
  float*    cur1   = (float*)d_ws;
  uint32_t* masks  = (uint32_t*)((char*)d_ws + MASKS_OFF);
  ushort_t* wp     = (ushort_t*)((char*)d_ws + WP_OFF);
  uint32_t* thresh = (uint32_t*)((char*)d_ws + THR_OFF);

  prep       <<<dim3(3328), dim3(256), 0, stream>>>(w1, x, wp, thresh);
  spike_gemm <<<dim3(1280), dim3(256), 0, stream>>>(thresh, wp, b1, cur1);
  lif1_spikes<<<dim3(512),  dim3(256), 0, stream>>>(cur1, masks);
  lif2_seq   <<<dim3(256),  dim3(320), 0, stream>>>(w2, b2, masks, out);
}